// Round 6
// baseline (201.576 us; speedup 1.0000x reference)
//
#include <hip/hip_runtime.h>
#include <hip/hip_bf16.h>

// LSTM cell, B=65536, I=H=128, fp32 I/O. R9: 4-wave blocks + freed regs.
// R8b post-mortem: VGPR_Count=56 under __launch_bounds__(512,4) proves the
// allocator serialized the ~28 startup loads (reused dest regs) -> 1.7 TB/s
// Little's-law limit. R9: 4096 blocks x 256 threads (4 waves); block = 32
// rows x 64 j (x4 gates). Fine occupancy quanta (4-wave blocks), cap ~170
// regs via __launch_bounds__(256,3) so all loads stay in flight; weight
// stream deepened to 4 (covers ~300cy L2 latency; R8b's 2-deep left ~150cy
// exposed per ks pair). Convert-on-stage fragment LDS kept (conflicts 0,
// cvt deduped); raw lgkmcnt(0)+s_barrier keeps vmem in flight.

typedef short s16x8 __attribute__((ext_vector_type(8)));
typedef float f32x4 __attribute__((ext_vector_type(4)));

__device__ __forceinline__ short f2bf(float f) {
    __hip_bfloat16 h = __float2bfloat16(f);
    return __builtin_bit_cast(short, h);
}
__device__ __forceinline__ float sigm(float x) { return 1.0f / (1.0f + __expf(-x)); }
__device__ __forceinline__ float tanh_f(float x) { return 1.0f - 2.0f / (1.0f + __expf(2.0f * x)); }

// ---- kernel 1: repack 8 fp32 weight mats -> bf16 MFMA-fragment order ----
// Frag fi = (jt16*4 + g)*8 + ks  (256 frags x 1 KB). Lane l of frag holds
// W[g][j = jt16*16 + (l&15)][k = ks*32 + (l>>4)*8 .. +8), k<128 from W_x,
// k>=128 from W_h (k-128). Element order: v[0..3]=k+0..3, v[4..7]=k+4..7.
__global__ __launch_bounds__(256)
void repack_weights(const float* __restrict__ Wii, const float* __restrict__ Whi,
                    const float* __restrict__ Wif, const float* __restrict__ Whf,
                    const float* __restrict__ Wig, const float* __restrict__ Whg,
                    const float* __restrict__ Wio, const float* __restrict__ Who,
                    short* __restrict__ ws)
{
    const int t   = blockIdx.x * 256 + threadIdx.x;   // 16384 threads
    const int fi  = t >> 6;
    const int l   = t & 63;
    const int ks  = fi & 7;
    const int g   = (fi >> 3) & 3;
    const int jt  = fi >> 5;
    const int j   = jt * 16 + (l & 15);
    const int k   = ks * 32 + (l >> 4) * 8;

    const float* wx = (g == 0) ? Wii : (g == 1) ? Wif : (g == 2) ? Wig : Wio;
    const float* wh = (g == 0) ? Whi : (g == 1) ? Whf : (g == 2) ? Whg : Who;
    const float* src = (k < 128) ? (wx + (size_t)j * 128 + k)
                                 : (wh + (size_t)j * 128 + (k - 128));
    f32x4 a = *(const f32x4*)src;
    f32x4 b = *(const f32x4*)(src + 4);
    s16x8 v;
#pragma unroll
    for (int q = 0; q < 4; ++q) { v[q] = f2bf(a[q]); v[4 + q] = f2bf(b[q]); }
    *(s16x8*)(ws + (size_t)t * 8) = v;
}

// ---- kernel 2: main fused LSTM (one 32-row x 64-j tile per block) ----
__global__ __launch_bounds__(256, 3)
void lstm_cell_kernel(const float* __restrict__ X,
                      const float* __restrict__ H,
                      const float* __restrict__ C,
                      const float* __restrict__ Bi, const float* __restrict__ Bf,
                      const float* __restrict__ Bg, const float* __restrict__ Bo,
                      const short* __restrict__ WS,
                      float* __restrict__ OutH,
                      float* __restrict__ OutC)
{
    __shared__ __align__(16) char sA[16384];   // 16 A-frags x 1 KB

    const int tid = threadIdx.x;
    const int l   = tid & 63;
    const int w   = tid >> 6;          // 0..3
    const int lj  = l & 15;
    const int lq  = l >> 4;
    const int qb  = blockIdx.x & 1;    // j col-half
    const int B0  = (blockIdx.x >> 1) * 32;
    const int jt16 = qb * 4 + w;       // this wave's 16-j group index
    const int jw   = jt16 * 16 + lj;   // this lane's j (all 4 gates)

    // ---- issue A loads: wave w stages frags ks = 2w, 2w+1 (mt = 0,1) ----
    // ks<4 from X (k = ks*32..), ks>=4 from H (k-128).
    const float* abase = (w < 2) ? X : H;
    f32x4 sa[2][2], sb[2][2];          // [s][mt], ks = 2w+s
#pragma unroll
    for (int s = 0; s < 2; ++s) {
        const int kloc = (((2 * w + s) & 3) * 32) + lq * 8;
#pragma unroll
        for (int mt = 0; mt < 2; ++mt) {
            const float* p = abase + (size_t)(B0 + mt * 16 + lj) * 128 + kloc;
            sa[s][mt] = *(const f32x4*)p;
            sb[s][mt] = *(const f32x4*)(p + 4);
        }
    }

    // ---- issue weight preload (ks 0..3, 4-deep), C prefetch, biases ----
    const short* wsw = WS + (size_t)jt16 * 32 * 512 + (size_t)l * 8;
    s16x8 wbuf[4][4];                  // [depth][g], 4-deep stream ring
#pragma unroll
    for (int d = 0; d < 4; ++d)
#pragma unroll
        for (int g = 0; g < 4; ++g)
            wbuf[d][g] = *(const s16x8*)(wsw + (size_t)(g * 8 + d) * 512);

    float cpv[8];
#pragma unroll
    for (int mt = 0; mt < 2; ++mt)
#pragma unroll
        for (int r = 0; r < 4; ++r)
            cpv[mt * 4 + r] = C[(size_t)(B0 + mt * 16 + lq * 4 + r) * 128 + jw];

    const float bi  = Bi[jw];
    const float bfv = Bf[jw];
    const float bg  = Bg[jw];
    const float bo  = Bo[jw];

    // ---- stage: cvt fp32->bf16, write own 4 frags (compiler waits sa/sb) ----
#pragma unroll
    for (int s = 0; s < 2; ++s)
#pragma unroll
        for (int mt = 0; mt < 2; ++mt) {
            s16x8 v;
#pragma unroll
            for (int q = 0; q < 4; ++q) {
                v[q]     = f2bf(sa[s][mt][q]);
                v[4 + q] = f2bf(sb[s][mt][q]);
            }
            *(s16x8*)(sA + (mt * 8 + 2 * w + s) * 1024 + l * 16) = v;
        }
    // own ds_writes retired, then block barrier; vmem stays in flight.
    asm volatile("s_waitcnt lgkmcnt(0)\n\ts_barrier" ::: "memory");

    // ---- K-loop: 8 ks steps, 4-deep weight stream (static ring index) ----
    f32x4 acc[2][4];                   // [mt][g]
#pragma unroll
    for (int mt = 0; mt < 2; ++mt)
#pragma unroll
        for (int g = 0; g < 4; ++g)
            acc[mt][g] = (f32x4){0.f, 0.f, 0.f, 0.f};

#pragma unroll
    for (int ks = 0; ks < 8; ++ks) {
        const s16x8 af0 = *(const s16x8*)(sA + (0 * 8 + ks) * 1024 + l * 16);
        const s16x8 af1 = *(const s16x8*)(sA + (1 * 8 + ks) * 1024 + l * 16);
#pragma unroll
        for (int g = 0; g < 4; ++g) {
            acc[0][g] = __builtin_amdgcn_mfma_f32_16x16x32_bf16(af0, wbuf[ks & 3][g], acc[0][g], 0, 0, 0);
            acc[1][g] = __builtin_amdgcn_mfma_f32_16x16x32_bf16(af1, wbuf[ks & 3][g], acc[1][g], 0, 0, 0);
        }
        if (ks < 4) {                  // refill consumed slot with ks+4
#pragma unroll
            for (int g = 0; g < 4; ++g)
                wbuf[ks & 3][g] = *(const s16x8*)(wsw + (size_t)(g * 8 + ks + 4) * 512);
        }
    }

    // ---- epilogue: all 4 gates of (b,j) in-lane; C from prefetch ----
#pragma unroll
    for (int mt = 0; mt < 2; ++mt) {
#pragma unroll
        for (int r = 0; r < 4; ++r) {
            const int b = B0 + mt * 16 + lq * 4 + r;   // C/D: row=(lane>>4)*4+reg
            const size_t idx = (size_t)b * 128 + jw;
            const float ia = acc[mt][0][r] + bi;
            const float fa = acc[mt][1][r] + bfv;
            const float ga = acc[mt][2][r] + bg;
            const float oa = acc[mt][3][r] + bo;
            const float it = sigm(ia);
            const float ft = sigm(fa);
            const float gt = tanh_f(ga);
            const float ot = sigm(oa);
            const float co = cpv[mt * 4 + r];
            const float cn = ft * co + it * gt;
            const float hn = ot * tanh_f(cn);
            OutH[idx] = hn;
            OutC[idx] = cn;
        }
    }
}

extern "C" void kernel_launch(void* const* d_in, const int* in_sizes, int n_in,
                              void* d_out, int out_size, void* d_ws, size_t ws_size,
                              hipStream_t stream) {
    const float* X   = (const float*)d_in[0];
    const float* H   = (const float*)d_in[1];
    const float* C   = (const float*)d_in[2];
    const float* Wii = (const float*)d_in[3];
    const float* Whi = (const float*)d_in[4];
    const float* Bi  = (const float*)d_in[5];
    const float* Wif = (const float*)d_in[6];
    const float* Whf = (const float*)d_in[7];
    const float* Bf  = (const float*)d_in[8];
    const float* Wig = (const float*)d_in[9];
    const float* Whg = (const float*)d_in[10];
    const float* Bg  = (const float*)d_in[11];
    const float* Wio = (const float*)d_in[12];
    const float* Who = (const float*)d_in[13];
    const float* Bo  = (const float*)d_in[14];

    short* ws = (short*)d_ws;   // 256 KB bf16 fragment-ordered weights

    hipLaunchKernelGGL(repack_weights, dim3(64), dim3(256), 0, stream,
                       Wii, Whi, Wif, Whf, Wig, Whg, Wio, Who, ws);

    float* OutH = (float*)d_out;
    float* OutC = OutH + (size_t)65536 * 128;

    hipLaunchKernelGGL(lstm_cell_kernel, dim3(4096), dim3(256), 0, stream,
                       X, H, C, Bi, Bf, Bg, Bo, ws, OutH, OutC);
}